// Round 6
// baseline (159.626 us; speedup 1.0000x reference)
//
#include <hip/hip_runtime.h>
#include <hip/hip_bf16.h>

// Problem constants (fixed by the reference)
#define B_DIM   8
#define S_LEN   4096
#define H_DIM   1024
#define HID_DIM 128
#define NSPEC   5
#define NROWS   (HID_DIM + 1 + NSPEC)   // 129 interval rows + 5 special rows = 134
#define SLOPE   0.01f
#define LN_EPS  1e-12f
#define FUSE_BLOCKS 512                  // 2048 persistent waves

// native clang vector for nontemporal stores (HIP float4 is a class type,
// which __builtin_nontemporal_store rejects)
typedef float vfloat4 __attribute__((ext_vector_type(4)));

// ---------------------------------------------------------------------------
// Kernel 1: build table rows.
//   rows 0..128 : interval i -> (u_i, v_i) with expr_e(x) = x*u + v (b2 folded)
//   rows 129..133: special m -> (0, leaky(special_emb[m]) @ W2 + b2)
// Block 0 additionally publishes the raw breakpoints t_k (unsorted) for fuse;
// interval membership there is the order-independent count #{k: t_k <= x}.
// ---------------------------------------------------------------------------
__global__ __launch_bounds__(256) void build_kernel(
        const float* __restrict__ W1,
        const float* __restrict__ b1,
        const float* __restrict__ W2,
        const float* __restrict__ b2,
        const float* __restrict__ spec,
        float* __restrict__ tvals,
        float2* __restrict__ tab) {
    const int row = blockIdx.x;
    const int tid = threadIdx.x;

    __shared__ float tsh[HID_DIM];
    __shared__ float ash[HID_DIM];
    __shared__ float csh[HID_DIM];

    float w = 0.0f, b = 0.0f, t = 0.0f;
    if (tid < HID_DIM) {
        w = W1[tid];
        b = b1[tid];
        t = (w != 0.0f) ? (-b / w) : __builtin_inff();
        tsh[tid] = t;
        if (row == 0) tvals[tid] = t;    // raw breakpoints for the fuse ballot
    }
    __syncthreads();
    if (tid < HID_DIM) {
        // stable rank of t among all breakpoints (defines interval membership)
        int r = 0;
        #pragma unroll 8
        for (int k2 = 0; k2 < HID_DIM; ++k2) {
            const float t2 = tsh[k2];
            if (t2 < t || (t2 == t && k2 < tid)) ++r;
        }

        float a, c;
        if (row <= HID_DIM) {
            const bool crossed = (r < row);              // t_k <= x in interval
            bool zpos;
            if (w > 0.0f)      zpos = crossed;
            else if (w < 0.0f) zpos = !crossed;
            else               zpos = (b >= 0.0f);
            const float s = zpos ? 1.0f : (SLOPE * SLOPE);
            a = s * w;
            c = s * b;
        } else {
            const int m = row - (HID_DIM + 1);
            const float e = spec[m * HID_DIM + tid];
            a = 0.0f;
            c = (e >= 0.0f) ? e : SLOPE * e;
        }
        ash[tid] = a;
        csh[tid] = c;
    }
    __syncthreads();

    // thread handles columns [4*tid .. 4*tid+3]
    float4 u = make_float4(0.f, 0.f, 0.f, 0.f);
    float4 v = make_float4(0.f, 0.f, 0.f, 0.f);
    #pragma unroll 4
    for (int k = 0; k < HID_DIM; ++k) {
        const float4 w2 = reinterpret_cast<const float4*>(W2 + (size_t)k * H_DIM)[tid];
        const float a = ash[k], c = csh[k];
        u.x = fmaf(a, w2.x, u.x);  v.x = fmaf(c, w2.x, v.x);
        u.y = fmaf(a, w2.y, u.y);  v.y = fmaf(c, w2.y, v.y);
        u.z = fmaf(a, w2.z, u.z);  v.z = fmaf(c, w2.z, v.z);
        u.w = fmaf(a, w2.w, u.w);  v.w = fmaf(c, w2.w, v.w);
    }
    const float4 bb = reinterpret_cast<const float4*>(b2)[tid];
    float4* trow = reinterpret_cast<float4*>(tab + (size_t)row * H_DIM);
    trow[2 * tid]     = make_float4(u.x, v.x + bb.x, u.y, v.y + bb.y);
    trow[2 * tid + 1] = make_float4(u.z, v.z + bb.z, u.w, v.w + bb.w);
}

// ---------------------------------------------------------------------------
// Kernel 2: fused gather + table MLP + pos add + LayerNorm.
// Persistent waves, 2 tokens per wave-iteration, grid-stride over pairs with
// a 1-deep software pipeline: next pair's scalar heads + gathers are issued
// before the current pair's reduction/LN/store tail, so the load queue never
// drains. Zero LDS, zero barriers.
// ---------------------------------------------------------------------------
__global__ __launch_bounds__(256, 2) void fuse_kernel(
        const int*   __restrict__ gene_ids,
        const float* __restrict__ expr,
        const float* __restrict__ gene_emb,
        const float* __restrict__ pos_emb,
        const float* __restrict__ gamma,
        const float* __restrict__ beta,
        const float* __restrict__ tvals,
        const float2* __restrict__ tab,
        float* __restrict__ out,
        int npairs) {
    const int lane = threadIdx.x & 63;
    const int wv   = threadIdx.x >> 6;
    const int NW   = gridDim.x * 4;                 // total waves
    int pr = blockIdx.x * 4 + wv;                   // this wave's first pair
    if (pr >= npairs) return;

    // breakpoints + gamma/beta: loaded once per wave
    const float tka = tvals[lane];
    const float tkb = tvals[lane + 64];
    float4 gm[4], bt[4];
    #pragma unroll
    for (int q = 0; q < 4; ++q) {
        const int f = lane + 64 * q;
        gm[q] = reinterpret_cast<const float4*>(gamma)[f];
        bt[q] = reinterpret_cast<const float4*>(beta)[f];
    }

    // ---- prologue: scalars, rows, and gathers for the first pair
    float x0 = expr[2 * pr];
    float x1 = expr[2 * pr + 1];
    int gid0 = gene_ids[2 * pr];
    int gid1 = gene_ids[2 * pr + 1];

    float xm0, xm1;
    {
        const int rc0 = __popcll(__ballot(tka <= x0)) + __popcll(__ballot(tkb <= x0));
        const int rc1 = __popcll(__ballot(tka <= x1)) + __popcll(__ballot(tkb <= x1));
        const bool sA = (x0 < 0.0f), sB = (x1 < 0.0f);
        const int mA = min(max(-((int)x0) - 1, 0), NSPEC - 1);
        const int mB = min(max(-((int)x1) - 1, 0), NSPEC - 1);
        gid0 = gid0;  // keep
        xm0 = sA ? 0.0f : x0;
        xm1 = sB ? 0.0f : x1;
        const int row0 = sA ? (HID_DIM + 1 + mA) : rc0;
        const int row1 = sB ? (HID_DIM + 1 + mB) : rc1;
        // stash row pointers via registers below
        x0 = __int_as_float(row0);   // reuse x0/x1 slots to carry rows
        x1 = __int_as_float(row1);
    }
    int row0 = __float_as_int(x0);
    int row1 = __float_as_int(x1);

    float4 g0[4], g1[4], p0[4], p1[4], a0[4], b0[4], a1[4], b1v[4];
    {
        const int sp0 = (2 * pr) & (S_LEN - 1);
        const float4* gp0 = reinterpret_cast<const float4*>(gene_emb + (size_t)gid0 * H_DIM);
        const float4* gp1 = reinterpret_cast<const float4*>(gene_emb + (size_t)gid1 * H_DIM);
        const float4* pp0 = reinterpret_cast<const float4*>(pos_emb  + (size_t)sp0  * H_DIM);
        const float4* pp1 = pp0 + (H_DIM / 4);
        const float4* tp0 = reinterpret_cast<const float4*>(tab + (size_t)row0 * H_DIM);
        const float4* tp1 = reinterpret_cast<const float4*>(tab + (size_t)row1 * H_DIM);
        #pragma unroll
        for (int q = 0; q < 4; ++q) {
            const int f = lane + 64 * q;
            g0[q]  = gp0[f];
            g1[q]  = gp1[f];
            p0[q]  = pp0[f];
            p1[q]  = pp1[f];
            a0[q]  = tp0[2 * f];
            b0[q]  = tp0[2 * f + 1];
            a1[q]  = tp1[2 * f];
            b1v[q] = tp1[2 * f + 1];
        }
    }

    for (;;) {
        const int pn   = pr + NW;
        const bool more = (pn < npairs);

        // ---- issue next pair's scalar heads first (latency hidden below)
        float nx0 = 0.0f, nx1 = 0.0f;
        int  ng0 = 0, ng1 = 0;
        if (more) {
            nx0 = expr[2 * pn];
            nx1 = expr[2 * pn + 1];
            ng0 = gene_ids[2 * pn];
            ng1 = gene_ids[2 * pn + 1];
        }

        // ---- consume current gathers into e + moments (frees g/p/a/b regs)
        float4 e0[4], e1[4];
        float s1_0 = 0.0f, s2_0 = 0.0f, s1_1 = 0.0f, s2_1 = 0.0f;
        #pragma unroll
        for (int q = 0; q < 4; ++q) {
            float4 ev;
            ev.x = g0[q].x + fmaf(xm0, a0[q].x, a0[q].y) + p0[q].x;
            ev.y = g0[q].y + fmaf(xm0, a0[q].z, a0[q].w) + p0[q].y;
            ev.z = g0[q].z + fmaf(xm0, b0[q].x, b0[q].y) + p0[q].z;
            ev.w = g0[q].w + fmaf(xm0, b0[q].z, b0[q].w) + p0[q].w;
            e0[q] = ev;
            s1_0 += ev.x + ev.y + ev.z + ev.w;
            s2_0 += ev.x * ev.x + ev.y * ev.y + ev.z * ev.z + ev.w * ev.w;

            float4 fv;
            fv.x = g1[q].x + fmaf(xm1, a1[q].x, a1[q].y) + p1[q].x;
            fv.y = g1[q].y + fmaf(xm1, a1[q].z, a1[q].w) + p1[q].y;
            fv.z = g1[q].z + fmaf(xm1, b1v[q].x, b1v[q].y) + p1[q].z;
            fv.w = g1[q].w + fmaf(xm1, b1v[q].z, b1v[q].w) + p1[q].w;
            e1[q] = fv;
            s1_1 += fv.x + fv.y + fv.z + fv.w;
            s2_1 += fv.x * fv.x + fv.y * fv.y + fv.z * fv.z + fv.w * fv.w;
        }

        // ---- ballot + issue next pair's gathers into the freed registers
        float nxm0 = 0.0f, nxm1 = 0.0f;
        if (more) {
            const int rc0 = __popcll(__ballot(tka <= nx0)) + __popcll(__ballot(tkb <= nx0));
            const int rc1 = __popcll(__ballot(tka <= nx1)) + __popcll(__ballot(tkb <= nx1));
            const bool sA = (nx0 < 0.0f), sB = (nx1 < 0.0f);
            const int mA = min(max(-((int)nx0) - 1, 0), NSPEC - 1);
            const int mB = min(max(-((int)nx1) - 1, 0), NSPEC - 1);
            const int nrow0 = sA ? (HID_DIM + 1 + mA) : rc0;
            const int nrow1 = sB ? (HID_DIM + 1 + mB) : rc1;
            nxm0 = sA ? 0.0f : nx0;
            nxm1 = sB ? 0.0f : nx1;

            const int sp0 = (2 * pn) & (S_LEN - 1);
            const float4* gp0 = reinterpret_cast<const float4*>(gene_emb + (size_t)ng0 * H_DIM);
            const float4* gp1 = reinterpret_cast<const float4*>(gene_emb + (size_t)ng1 * H_DIM);
            const float4* pp0 = reinterpret_cast<const float4*>(pos_emb  + (size_t)sp0 * H_DIM);
            const float4* pp1 = pp0 + (H_DIM / 4);
            const float4* tp0 = reinterpret_cast<const float4*>(tab + (size_t)nrow0 * H_DIM);
            const float4* tp1 = reinterpret_cast<const float4*>(tab + (size_t)nrow1 * H_DIM);
            #pragma unroll
            for (int q = 0; q < 4; ++q) {
                const int f = lane + 64 * q;
                g0[q]  = gp0[f];
                g1[q]  = gp1[f];
                p0[q]  = pp0[f];
                p1[q]  = pp1[f];
                a0[q]  = tp0[2 * f];
                b0[q]  = tp0[2 * f + 1];
                a1[q]  = tp1[2 * f];
                b1v[q] = tp1[2 * f + 1];
            }
        }

        // ---- current pair's reduction + LN + store (hides next's latency)
        #pragma unroll
        for (int off = 32; off >= 1; off >>= 1) {
            s1_0 += __shfl_xor(s1_0, off, 64);
            s2_0 += __shfl_xor(s2_0, off, 64);
            s1_1 += __shfl_xor(s1_1, off, 64);
            s2_1 += __shfl_xor(s2_1, off, 64);
        }
        const float inv  = 1.0f / (float)H_DIM;
        const float mu0  = s1_0 * inv;
        const float rs0  = rsqrtf(s2_0 * inv - mu0 * mu0 + LN_EPS);
        const float mu1  = s1_1 * inv;
        const float rs1  = rsqrtf(s2_1 * inv - mu1 * mu1 + LN_EPS);

        vfloat4* op0 = reinterpret_cast<vfloat4*>(out + (size_t)(2 * pr) * H_DIM);
        vfloat4* op1 = op0 + (H_DIM / 4);
        #pragma unroll
        for (int q = 0; q < 4; ++q) {
            const int f = lane + 64 * q;
            vfloat4 o;
            o.x = fmaf((e0[q].x - mu0) * rs0, gm[q].x, bt[q].x);
            o.y = fmaf((e0[q].y - mu0) * rs0, gm[q].y, bt[q].y);
            o.z = fmaf((e0[q].z - mu0) * rs0, gm[q].z, bt[q].z);
            o.w = fmaf((e0[q].w - mu0) * rs0, gm[q].w, bt[q].w);
            __builtin_nontemporal_store(o, op0 + f);
            vfloat4 o2;
            o2.x = fmaf((e1[q].x - mu1) * rs1, gm[q].x, bt[q].x);
            o2.y = fmaf((e1[q].y - mu1) * rs1, gm[q].y, bt[q].y);
            o2.z = fmaf((e1[q].z - mu1) * rs1, gm[q].z, bt[q].z);
            o2.w = fmaf((e1[q].w - mu1) * rs1, gm[q].w, bt[q].w);
            __builtin_nontemporal_store(o2, op1 + f);
        }

        if (!more) break;
        pr  = pn;
        xm0 = nxm0;
        xm1 = nxm1;
    }
}

// ---------------------------------------------------------------------------
extern "C" void kernel_launch(void* const* d_in, const int* in_sizes, int n_in,
                              void* d_out, int out_size, void* d_ws, size_t ws_size,
                              hipStream_t stream) {
    const int*   gene_ids = (const int*)  d_in[0];
    const float* expr     = (const float*)d_in[1];
    const float* gene_emb = (const float*)d_in[2];
    const float* W1       = (const float*)d_in[3];
    const float* b1       = (const float*)d_in[4];
    const float* W2       = (const float*)d_in[5];
    const float* b2       = (const float*)d_in[6];
    const float* spec     = (const float*)d_in[7];
    const float* pos_emb  = (const float*)d_in[8];
    const float* gamma    = (const float*)d_in[9];
    const float* beta     = (const float*)d_in[10];
    float* out = (float*)d_out;

    // workspace layout
    const size_t tab_bytes = (size_t)NROWS * H_DIM * sizeof(float2);  // ~1.07 MB
    float2* tab   = (float2*)d_ws;
    float*  tvals = (float*)((char*)d_ws + tab_bytes);

    const int n_tokens = in_sizes[0];   // B*S = 32768
    const int npairs   = n_tokens / 2;  // 16384

    build_kernel<<<NROWS, 256, 0, stream>>>(W1, b1, W2, b2, spec, tvals, tab);
    fuse_kernel<<<FUSE_BLOCKS, 256, 0, stream>>>(gene_ids, expr, gene_emb, pos_emb,
                                                 gamma, beta, tvals, tab, out, npairs);
}

// Round 7
// 73.946 us; speedup vs baseline: 2.1587x; 2.1587x over previous
//
#include <hip/hip_runtime.h>
#include <hip/hip_bf16.h>

// Problem constants (fixed by the reference)
#define B_DIM   8
#define S_LEN   4096
#define H_DIM   1024
#define HID_DIM 128
#define NSPEC   5
#define NROWS   (HID_DIM + 1 + NSPEC)   // 129 interval rows + 5 special rows = 134
#define SLOPE   0.01f
#define LN_EPS  1e-12f

// native clang vector for nontemporal stores (HIP float4 is a class type,
// which __builtin_nontemporal_store rejects)
typedef float vfloat4 __attribute__((ext_vector_type(4)));

// ---------------------------------------------------------------------------
// Kernel 1: build table rows.
//   rows 0..128 : interval i -> (u_i, v_i) with expr_e(x) = x*u + v (b2 folded)
//   rows 129..133: special m -> (0, leaky(special_emb[m]) @ W2 + b2)
// Block 0 additionally publishes the raw breakpoints t_k (unsorted) for fuse;
// interval membership there is the order-independent count #{k: t_k <= x}.
// ---------------------------------------------------------------------------
__global__ __launch_bounds__(256) void build_kernel(
        const float* __restrict__ W1,
        const float* __restrict__ b1,
        const float* __restrict__ W2,
        const float* __restrict__ b2,
        const float* __restrict__ spec,
        float* __restrict__ tvals,
        float2* __restrict__ tab) {
    const int row = blockIdx.x;
    const int tid = threadIdx.x;

    __shared__ float tsh[HID_DIM];
    __shared__ float ash[HID_DIM];
    __shared__ float csh[HID_DIM];

    float w = 0.0f, b = 0.0f, t = 0.0f;
    if (tid < HID_DIM) {
        w = W1[tid];
        b = b1[tid];
        t = (w != 0.0f) ? (-b / w) : __builtin_inff();
        tsh[tid] = t;
        if (row == 0) tvals[tid] = t;    // raw breakpoints for the fuse ballot
    }
    __syncthreads();
    if (tid < HID_DIM) {
        // stable rank of t among all breakpoints (defines interval membership)
        int r = 0;
        #pragma unroll 8
        for (int k2 = 0; k2 < HID_DIM; ++k2) {
            const float t2 = tsh[k2];
            if (t2 < t || (t2 == t && k2 < tid)) ++r;
        }

        float a, c;
        if (row <= HID_DIM) {
            const bool crossed = (r < row);              // t_k <= x in interval
            bool zpos;
            if (w > 0.0f)      zpos = crossed;
            else if (w < 0.0f) zpos = !crossed;
            else               zpos = (b >= 0.0f);
            const float s = zpos ? 1.0f : (SLOPE * SLOPE);
            a = s * w;
            c = s * b;
        } else {
            const int m = row - (HID_DIM + 1);
            const float e = spec[m * HID_DIM + tid];
            a = 0.0f;
            c = (e >= 0.0f) ? e : SLOPE * e;
        }
        ash[tid] = a;
        csh[tid] = c;
    }
    __syncthreads();

    // thread handles columns [4*tid .. 4*tid+3]
    float4 u = make_float4(0.f, 0.f, 0.f, 0.f);
    float4 v = make_float4(0.f, 0.f, 0.f, 0.f);
    #pragma unroll 4
    for (int k = 0; k < HID_DIM; ++k) {
        const float4 w2 = reinterpret_cast<const float4*>(W2 + (size_t)k * H_DIM)[tid];
        const float a = ash[k], c = csh[k];
        u.x = fmaf(a, w2.x, u.x);  v.x = fmaf(c, w2.x, v.x);
        u.y = fmaf(a, w2.y, u.y);  v.y = fmaf(c, w2.y, v.y);
        u.z = fmaf(a, w2.z, u.z);  v.z = fmaf(c, w2.z, v.z);
        u.w = fmaf(a, w2.w, u.w);  v.w = fmaf(c, w2.w, v.w);
    }
    const float4 bb = reinterpret_cast<const float4*>(b2)[tid];
    float4* trow = reinterpret_cast<float4*>(tab + (size_t)row * H_DIM);
    trow[2 * tid]     = make_float4(u.x, v.x + bb.x, u.y, v.y + bb.y);
    trow[2 * tid + 1] = make_float4(u.z, v.z + bb.z, u.w, v.w + bb.w);
}

// ---------------------------------------------------------------------------
// Kernel 2: fused gather + table MLP + pos add + LayerNorm.
// ONE token per wave, VGPR <= 128 (__launch_bounds__(256,4)) so 4 waves/SIMD
// are resident -> 16 waves/CU, 2x the outstanding load bytes of the 2-token
// variant (which sits in the 129-256 VGPR band at 2 waves/SIMD).
// gamma/beta are loaded LATE (after staging regs are consumed) to keep the
// peak register window small; their latency hides under the shfl reduction.
// Zero LDS, zero barriers.
// ---------------------------------------------------------------------------
__global__ __launch_bounds__(256, 4) void fuse_kernel(
        const int*   __restrict__ gene_ids,
        const float* __restrict__ expr,
        const float* __restrict__ gene_emb,
        const float* __restrict__ pos_emb,
        const float* __restrict__ gamma,
        const float* __restrict__ beta,
        const float* __restrict__ tvals,
        const float2* __restrict__ tab,
        float* __restrict__ out) {
    const int tid  = threadIdx.x;
    const int lane = tid & 63;
    const int t    = blockIdx.x * 4 + (tid >> 6);   // token index
    const int sp   = t & (S_LEN - 1);               // S = 4096 (pow2)

    // scalar heads + breakpoints: all issue immediately
    const float x   = expr[t];                      // wave-uniform broadcast
    const int   gid = gene_ids[t];
    const float tka = tvals[lane];
    const float tkb = tvals[lane + 64];

    const float4* gp = reinterpret_cast<const float4*>(gene_emb + (size_t)gid * H_DIM);
    const float4* pp = reinterpret_cast<const float4*>(pos_emb  + (size_t)sp  * H_DIM);

    // gene + pos gathers (independent of the ballot)
    float4 g[4], p[4];
    #pragma unroll
    for (int q = 0; q < 4; ++q) {
        const int f = lane + 64 * q;
        g[q] = gp[f];
        p[q] = pp[f];
    }

    // interval row via ballot+popcount (x is wave-uniform)
    const int rc = __popcll(__ballot(tka <= x)) + __popcll(__ballot(tkb <= x));
    const bool spec = (x < 0.0f);
    const int  msp  = min(max(-((int)x) - 1, 0), NSPEC - 1);
    const int  row  = spec ? (HID_DIM + 1 + msp) : rc;
    const float xm  = spec ? 0.0f : x;              // special u-rows are zero

    // table row
    const float4* tp = reinterpret_cast<const float4*>(tab + (size_t)row * H_DIM);
    float4 ta[4], tb[4];
    #pragma unroll
    for (int q = 0; q < 4; ++q) {
        const int f = lane + 64 * q;
        ta[q] = tp[2 * f];          // (u0, v0, u1, v1)
        tb[q] = tp[2 * f + 1];      // (u2, v2, u3, v3)
    }

    // combine into e (staging registers are consumed here) + moments
    float4 e[4];
    float s1 = 0.0f, s2 = 0.0f;
    #pragma unroll
    for (int q = 0; q < 4; ++q) {
        float4 ev;
        ev.x = g[q].x + fmaf(xm, ta[q].x, ta[q].y) + p[q].x;
        ev.y = g[q].y + fmaf(xm, ta[q].z, ta[q].w) + p[q].y;
        ev.z = g[q].z + fmaf(xm, tb[q].x, tb[q].y) + p[q].z;
        ev.w = g[q].w + fmaf(xm, tb[q].z, tb[q].w) + p[q].w;
        e[q] = ev;
        s1 += ev.x + ev.y + ev.z + ev.w;
        s2 += ev.x * ev.x + ev.y * ev.y + ev.z * ev.z + ev.w * ev.w;
    }

    // gamma/beta loads issue here (L1/L2-hot); latency hides under reduction
    float4 gm[4], bt[4];
    #pragma unroll
    for (int q = 0; q < 4; ++q) {
        const int f = lane + 64 * q;
        gm[q] = reinterpret_cast<const float4*>(gamma)[f];
        bt[q] = reinterpret_cast<const float4*>(beta)[f];
    }

    // 64-lane butterfly reduction (no LDS, no barrier)
    #pragma unroll
    for (int off = 32; off >= 1; off >>= 1) {
        s1 += __shfl_xor(s1, off, 64);
        s2 += __shfl_xor(s2, off, 64);
    }

    const float inv  = 1.0f / (float)H_DIM;
    const float mu   = s1 * inv;
    const float rsig = rsqrtf(s2 * inv - mu * mu + LN_EPS);

    vfloat4* op = reinterpret_cast<vfloat4*>(out + (size_t)t * H_DIM);
    #pragma unroll
    for (int q = 0; q < 4; ++q) {
        const int f = lane + 64 * q;
        vfloat4 o;
        o.x = fmaf((e[q].x - mu) * rsig, gm[q].x, bt[q].x);
        o.y = fmaf((e[q].y - mu) * rsig, gm[q].y, bt[q].y);
        o.z = fmaf((e[q].z - mu) * rsig, gm[q].z, bt[q].z);
        o.w = fmaf((e[q].w - mu) * rsig, gm[q].w, bt[q].w);
        __builtin_nontemporal_store(o, op + f);
    }
}

// ---------------------------------------------------------------------------
extern "C" void kernel_launch(void* const* d_in, const int* in_sizes, int n_in,
                              void* d_out, int out_size, void* d_ws, size_t ws_size,
                              hipStream_t stream) {
    const int*   gene_ids = (const int*)  d_in[0];
    const float* expr     = (const float*)d_in[1];
    const float* gene_emb = (const float*)d_in[2];
    const float* W1       = (const float*)d_in[3];
    const float* b1       = (const float*)d_in[4];
    const float* W2       = (const float*)d_in[5];
    const float* b2       = (const float*)d_in[6];
    const float* spec     = (const float*)d_in[7];
    const float* pos_emb  = (const float*)d_in[8];
    const float* gamma    = (const float*)d_in[9];
    const float* beta     = (const float*)d_in[10];
    float* out = (float*)d_out;

    // workspace layout
    const size_t tab_bytes = (size_t)NROWS * H_DIM * sizeof(float2);  // ~1.07 MB
    float2* tab   = (float2*)d_ws;
    float*  tvals = (float*)((char*)d_ws + tab_bytes);

    const int n_tokens = in_sizes[0];   // B*S = 32768

    build_kernel<<<NROWS, 256, 0, stream>>>(W1, b1, W2, b2, spec, tvals, tab);
    fuse_kernel<<<n_tokens / 4, 256, 0, stream>>>(gene_ids, expr, gene_emb, pos_emb,
                                                  gamma, beta, tvals, tab, out);
}

// Round 8
// 67.890 us; speedup vs baseline: 2.3512x; 1.0892x over previous
//
#include <hip/hip_runtime.h>
#include <hip/hip_bf16.h>

// Problem constants (fixed by the reference)
#define B_DIM   8
#define S_LEN   4096
#define H_DIM   1024
#define HID_DIM 128
#define NSPEC   5
#define NROWS   (HID_DIM + 1 + NSPEC)   // 129 interval rows + 5 special rows = 134
#define SLOPE   0.01f
#define LN_EPS  1e-12f
#define FUSE_GRID 2048                   // x4 grid-stride iters = 8192 groups

// native clang vector for nontemporal stores (HIP float4 is a class type,
// which __builtin_nontemporal_store rejects)
typedef float vfloat4 __attribute__((ext_vector_type(4)));

// ---------------------------------------------------------------------------
// Kernel 1: build table rows.
//   rows 0..128 : interval i -> (u_i, v_i) with expr_e(x) = x*u + v (b2 folded)
//   rows 129..133: special m -> (0, leaky(special_emb[m]) @ W2 + b2)
// Block 0 additionally publishes the raw breakpoints t_k (unsorted) for fuse;
// interval membership there is the order-independent count #{k: t_k <= x}.
// ---------------------------------------------------------------------------
__global__ __launch_bounds__(256) void build_kernel(
        const float* __restrict__ W1,
        const float* __restrict__ b1,
        const float* __restrict__ W2,
        const float* __restrict__ b2,
        const float* __restrict__ spec,
        float* __restrict__ tvals,
        float2* __restrict__ tab) {
    const int row = blockIdx.x;
    const int tid = threadIdx.x;

    __shared__ float tsh[HID_DIM];
    __shared__ float ash[HID_DIM];
    __shared__ float csh[HID_DIM];

    float w = 0.0f, b = 0.0f, t = 0.0f;
    if (tid < HID_DIM) {
        w = W1[tid];
        b = b1[tid];
        t = (w != 0.0f) ? (-b / w) : __builtin_inff();
        tsh[tid] = t;
        if (row == 0) tvals[tid] = t;    // raw breakpoints for the fuse ballot
    }
    __syncthreads();
    if (tid < HID_DIM) {
        // stable rank of t among all breakpoints (defines interval membership)
        int r = 0;
        #pragma unroll 8
        for (int k2 = 0; k2 < HID_DIM; ++k2) {
            const float t2 = tsh[k2];
            if (t2 < t || (t2 == t && k2 < tid)) ++r;
        }

        float a, c;
        if (row <= HID_DIM) {
            const bool crossed = (r < row);              // t_k <= x in interval
            bool zpos;
            if (w > 0.0f)      zpos = crossed;
            else if (w < 0.0f) zpos = !crossed;
            else               zpos = (b >= 0.0f);
            const float s = zpos ? 1.0f : (SLOPE * SLOPE);
            a = s * w;
            c = s * b;
        } else {
            const int m = row - (HID_DIM + 1);
            const float e = spec[m * HID_DIM + tid];
            a = 0.0f;
            c = (e >= 0.0f) ? e : SLOPE * e;
        }
        ash[tid] = a;
        csh[tid] = c;
    }
    __syncthreads();

    // thread handles columns [4*tid .. 4*tid+3]
    float4 u = make_float4(0.f, 0.f, 0.f, 0.f);
    float4 v = make_float4(0.f, 0.f, 0.f, 0.f);
    #pragma unroll 4
    for (int k = 0; k < HID_DIM; ++k) {
        const float4 w2 = reinterpret_cast<const float4*>(W2 + (size_t)k * H_DIM)[tid];
        const float a = ash[k], c = csh[k];
        u.x = fmaf(a, w2.x, u.x);  v.x = fmaf(c, w2.x, v.x);
        u.y = fmaf(a, w2.y, u.y);  v.y = fmaf(c, w2.y, v.y);
        u.z = fmaf(a, w2.z, u.z);  v.z = fmaf(c, w2.z, v.z);
        u.w = fmaf(a, w2.w, u.w);  v.w = fmaf(c, w2.w, v.w);
    }
    const float4 bb = reinterpret_cast<const float4*>(b2)[tid];
    float4* trow = reinterpret_cast<float4*>(tab + (size_t)row * H_DIM);
    trow[2 * tid]     = make_float4(u.x, v.x + bb.x, u.y, v.y + bb.y);
    trow[2 * tid + 1] = make_float4(u.z, v.z + bb.z, u.w, v.w + bb.w);
}

// ---------------------------------------------------------------------------
// Kernel 2: fused gather + table MLP + pos add + LayerNorm.
// One token per wave; persistent grid-stride (2048 blocks, 4 iters).
// L1/TCP traffic diet vs R7:
//  - gamma/beta staged in LDS once per block (DS pipe, not TCP): -8 KB/token
//  - group stride = gridDim (2048) => token stride 8192 == 0 mod S, so each
//    wave's pos row is IDENTICAL across iterations: loaded once, kept in
//    registers: -4 KB/token after iter 0.
// Token L1 bytes: 24 KB -> 12 KB (gene 4K + tab 8K).
// ---------------------------------------------------------------------------
__global__ __launch_bounds__(256, 4) void fuse_kernel(
        const int*   __restrict__ gene_ids,
        const float* __restrict__ expr,
        const float* __restrict__ gene_emb,
        const float* __restrict__ pos_emb,
        const float* __restrict__ gamma,
        const float* __restrict__ beta,
        const float* __restrict__ tvals,
        const float2* __restrict__ tab,
        float* __restrict__ out,
        int ngroups) {
    const int tid  = threadIdx.x;
    const int lane = tid & 63;
    const int wv   = tid >> 6;

    __shared__ float4 gm_lds[H_DIM / 4];   // 4 KB
    __shared__ float4 bt_lds[H_DIM / 4];   // 4 KB
    gm_lds[tid] = reinterpret_cast<const float4*>(gamma)[tid];
    bt_lds[tid] = reinterpret_cast<const float4*>(beta)[tid];

    // breakpoints: once per wave
    const float tka = tvals[lane];
    const float tkb = tvals[lane + 64];

    // pos row: token stride per iteration is 4*gridDim = 8192 = 2*S_LEN,
    // so s is invariant for this wave -> load once.
    const int t_first = blockIdx.x * 4 + wv;
    const int sp      = t_first & (S_LEN - 1);
    const float4* pp  = reinterpret_cast<const float4*>(pos_emb + (size_t)sp * H_DIM);
    float4 p[4];
    #pragma unroll
    for (int q = 0; q < 4; ++q) p[q] = pp[lane + 64 * q];

    __syncthreads();    // gamma/beta staged

    // prefetched scalar heads for the first iteration
    float x   = expr[t_first];
    int   gid = gene_ids[t_first];

    for (int grp = blockIdx.x; grp < ngroups; grp += gridDim.x) {
        const int t = grp * 4 + wv;

        // issue next iteration's scalar heads early (latency hides under body)
        const int tn = t + 4 * gridDim.x;
        float nx  = 0.0f;
        int   ngid = 0;
        if (tn < 4 * ngroups) {
            nx   = expr[tn];
            ngid = gene_ids[tn];
        }

        // gene gather (independent of ballot)
        const float4* gp = reinterpret_cast<const float4*>(gene_emb + (size_t)gid * H_DIM);
        float4 g[4];
        #pragma unroll
        for (int q = 0; q < 4; ++q) g[q] = gp[lane + 64 * q];

        // interval row via ballot+popcount (x is wave-uniform)
        const int rc = __popcll(__ballot(tka <= x)) + __popcll(__ballot(tkb <= x));
        const bool spc = (x < 0.0f);
        const int  msp = min(max(-((int)x) - 1, 0), NSPEC - 1);
        const int  row = spc ? (HID_DIM + 1 + msp) : rc;
        const float xm = spc ? 0.0f : x;            // special u-rows are zero

        // table row
        const float4* tp = reinterpret_cast<const float4*>(tab + (size_t)row * H_DIM);
        float4 ta[4], tb[4];
        #pragma unroll
        for (int q = 0; q < 4; ++q) {
            const int f = lane + 64 * q;
            ta[q] = tp[2 * f];          // (u0, v0, u1, v1)
            tb[q] = tp[2 * f + 1];      // (u2, v2, u3, v3)
        }

        // combine into e + moments
        float4 e[4];
        float s1 = 0.0f, s2 = 0.0f;
        #pragma unroll
        for (int q = 0; q < 4; ++q) {
            float4 ev;
            ev.x = g[q].x + fmaf(xm, ta[q].x, ta[q].y) + p[q].x;
            ev.y = g[q].y + fmaf(xm, ta[q].z, ta[q].w) + p[q].y;
            ev.z = g[q].z + fmaf(xm, tb[q].x, tb[q].y) + p[q].z;
            ev.w = g[q].w + fmaf(xm, tb[q].z, tb[q].w) + p[q].w;
            e[q] = ev;
            s1 += ev.x + ev.y + ev.z + ev.w;
            s2 += ev.x * ev.x + ev.y * ev.y + ev.z * ev.z + ev.w * ev.w;
        }

        // 64-lane butterfly reduction (no LDS, no barrier)
        #pragma unroll
        for (int off = 32; off >= 1; off >>= 1) {
            s1 += __shfl_xor(s1, off, 64);
            s2 += __shfl_xor(s2, off, 64);
        }

        const float inv  = 1.0f / (float)H_DIM;
        const float mu   = s1 * inv;
        const float rsig = rsqrtf(s2 * inv - mu * mu + LN_EPS);

        // gamma/beta from LDS (DS pipe); NT stores to out
        vfloat4* op = reinterpret_cast<vfloat4*>(out + (size_t)t * H_DIM);
        #pragma unroll
        for (int q = 0; q < 4; ++q) {
            const int f = lane + 64 * q;
            const float4 gm = gm_lds[f];
            const float4 bt = bt_lds[f];
            vfloat4 o;
            o.x = fmaf((e[q].x - mu) * rsig, gm.x, bt.x);
            o.y = fmaf((e[q].y - mu) * rsig, gm.y, bt.y);
            o.z = fmaf((e[q].z - mu) * rsig, gm.z, bt.z);
            o.w = fmaf((e[q].w - mu) * rsig, gm.w, bt.w);
            __builtin_nontemporal_store(o, op + f);
        }

        x   = nx;
        gid = ngid;
    }
}

// ---------------------------------------------------------------------------
extern "C" void kernel_launch(void* const* d_in, const int* in_sizes, int n_in,
                              void* d_out, int out_size, void* d_ws, size_t ws_size,
                              hipStream_t stream) {
    const int*   gene_ids = (const int*)  d_in[0];
    const float* expr     = (const float*)d_in[1];
    const float* gene_emb = (const float*)d_in[2];
    const float* W1       = (const float*)d_in[3];
    const float* b1       = (const float*)d_in[4];
    const float* W2       = (const float*)d_in[5];
    const float* b2       = (const float*)d_in[6];
    const float* spec     = (const float*)d_in[7];
    const float* pos_emb  = (const float*)d_in[8];
    const float* gamma    = (const float*)d_in[9];
    const float* beta     = (const float*)d_in[10];
    float* out = (float*)d_out;

    // workspace layout
    const size_t tab_bytes = (size_t)NROWS * H_DIM * sizeof(float2);  // ~1.07 MB
    float2* tab   = (float2*)d_ws;
    float*  tvals = (float*)((char*)d_ws + tab_bytes);

    const int n_tokens = in_sizes[0];   // B*S = 32768
    const int ngroups  = n_tokens / 4;  // 8192

    build_kernel<<<NROWS, 256, 0, stream>>>(W1, b1, W2, b2, spec, tvals, tab);
    fuse_kernel<<<FUSE_GRID, 256, 0, stream>>>(gene_ids, expr, gene_emb, pos_emb,
                                               gamma, beta, tvals, tab, out, ngroups);
}

// Round 9
// 64.752 us; speedup vs baseline: 2.4652x; 1.0485x over previous
//
#include <hip/hip_runtime.h>
#include <hip/hip_bf16.h>

// Problem constants (fixed by the reference)
#define B_DIM   8
#define S_LEN   4096
#define H_DIM   1024
#define HID_DIM 128
#define NSPEC   5
#define NROWS   (HID_DIM + 1 + NSPEC)   // 129 interval rows + 5 special rows = 134
#define SLOPE   0.01f
#define LN_EPS  1e-12f
#define NITER   8                        // tokens per wave (same pos row)

// native clang vector for nontemporal stores (HIP float4 is a class type,
// which __builtin_nontemporal_store rejects)
typedef float vfloat4 __attribute__((ext_vector_type(4)));

// ---------------------------------------------------------------------------
// Kernel 1: build table rows.
//   rows 0..128 : interval i -> (u_i, v_i) with expr_e(x) = x*u + v (b2 folded)
//   rows 129..133: special m -> (0, leaky(special_emb[m]) @ W2 + b2)
// Block 0 additionally publishes the raw breakpoints t_k (unsorted) for fuse;
// interval membership there is the order-independent count #{k: t_k <= x}.
// ---------------------------------------------------------------------------
__global__ __launch_bounds__(256) void build_kernel(
        const float* __restrict__ W1,
        const float* __restrict__ b1,
        const float* __restrict__ W2,
        const float* __restrict__ b2,
        const float* __restrict__ spec,
        float* __restrict__ tvals,
        float2* __restrict__ tab) {
    const int row = blockIdx.x;
    const int tid = threadIdx.x;

    __shared__ float tsh[HID_DIM];
    __shared__ float ash[HID_DIM];
    __shared__ float csh[HID_DIM];

    float w = 0.0f, b = 0.0f, t = 0.0f;
    if (tid < HID_DIM) {
        w = W1[tid];
        b = b1[tid];
        t = (w != 0.0f) ? (-b / w) : __builtin_inff();
        tsh[tid] = t;
        if (row == 0) tvals[tid] = t;    // raw breakpoints for the fuse ballot
    }
    __syncthreads();
    if (tid < HID_DIM) {
        // stable rank of t among all breakpoints (defines interval membership)
        int r = 0;
        #pragma unroll 8
        for (int k2 = 0; k2 < HID_DIM; ++k2) {
            const float t2 = tsh[k2];
            if (t2 < t || (t2 == t && k2 < tid)) ++r;
        }

        float a, c;
        if (row <= HID_DIM) {
            const bool crossed = (r < row);              // t_k <= x in interval
            bool zpos;
            if (w > 0.0f)      zpos = crossed;
            else if (w < 0.0f) zpos = !crossed;
            else               zpos = (b >= 0.0f);
            const float s = zpos ? 1.0f : (SLOPE * SLOPE);
            a = s * w;
            c = s * b;
        } else {
            const int m = row - (HID_DIM + 1);
            const float e = spec[m * HID_DIM + tid];
            a = 0.0f;
            c = (e >= 0.0f) ? e : SLOPE * e;
        }
        ash[tid] = a;
        csh[tid] = c;
    }
    __syncthreads();

    // thread handles columns [4*tid .. 4*tid+3]
    float4 u = make_float4(0.f, 0.f, 0.f, 0.f);
    float4 v = make_float4(0.f, 0.f, 0.f, 0.f);
    #pragma unroll 4
    for (int k = 0; k < HID_DIM; ++k) {
        const float4 w2 = reinterpret_cast<const float4*>(W2 + (size_t)k * H_DIM)[tid];
        const float a = ash[k], c = csh[k];
        u.x = fmaf(a, w2.x, u.x);  v.x = fmaf(c, w2.x, v.x);
        u.y = fmaf(a, w2.y, u.y);  v.y = fmaf(c, w2.y, v.y);
        u.z = fmaf(a, w2.z, u.z);  v.z = fmaf(c, w2.z, v.z);
        u.w = fmaf(a, w2.w, u.w);  v.w = fmaf(c, w2.w, v.w);
    }
    const float4 bb = reinterpret_cast<const float4*>(b2)[tid];
    float4* trow = reinterpret_cast<float4*>(tab + (size_t)row * H_DIM);
    trow[2 * tid]     = make_float4(u.x, v.x + bb.x, u.y, v.y + bb.y);
    trow[2 * tid + 1] = make_float4(u.z, v.z + bb.z, u.w, v.w + bb.w);
}

// ---------------------------------------------------------------------------
// Kernel 2: fused gather + table MLP + pos add + LayerNorm.
// One token per wave-iteration, NITER=8 tokens per wave, all sharing one
// pos row (token stride = S_LEN): pos loaded once into registers.
// Software pipeline: scalars 2-ahead, gene+tab rows 1-ahead, so each
// iteration consumes staging that is a full body old (gather latency
// hidden). gamma/beta in LDS. Register budget ~150 -> launch_bounds(256,2),
// no spill (R6's failure mode).
// ---------------------------------------------------------------------------
__global__ __launch_bounds__(256, 2) void fuse_kernel(
        const int*   __restrict__ gene_ids,
        const float* __restrict__ expr,
        const float* __restrict__ gene_emb,
        const float* __restrict__ pos_emb,
        const float* __restrict__ gamma,
        const float* __restrict__ beta,
        const float* __restrict__ tvals,
        const float2* __restrict__ tab,
        float* __restrict__ out) {
    const int tid  = threadIdx.x;
    const int lane = tid & 63;
    const int w    = blockIdx.x * 4 + (tid >> 6);   // wave id = pos row, 0..4095

    __shared__ float4 gm_lds[H_DIM / 4];   // 4 KB
    __shared__ float4 bt_lds[H_DIM / 4];   // 4 KB
    gm_lds[tid] = reinterpret_cast<const float4*>(gamma)[tid];
    bt_lds[tid] = reinterpret_cast<const float4*>(beta)[tid];

    // breakpoints + pos row: once per wave
    const float tka = tvals[lane];
    const float tkb = tvals[lane + 64];
    const float4* pp = reinterpret_cast<const float4*>(pos_emb + (size_t)w * H_DIM);
    float4 p[4];
    #pragma unroll
    for (int q = 0; q < 4; ++q) p[q] = pp[lane + 64 * q];

    __syncthreads();    // gamma/beta staged

    // ---- prologue: scalars for i=0,1; gene+tab staging for i=0
    float x_c  = expr[w];
    int   gd_c = gene_ids[w];
    float x_n  = expr[w + S_LEN];
    int   gd_n = gene_ids[w + S_LEN];

    float xm_c;
    float4 g_c[4], ta_c[4], tb_c[4];
    {
        const int rc = __popcll(__ballot(tka <= x_c)) + __popcll(__ballot(tkb <= x_c));
        const bool sc = (x_c < 0.0f);
        const int  mc = min(max(-((int)x_c) - 1, 0), NSPEC - 1);
        const int  row = sc ? (HID_DIM + 1 + mc) : rc;
        xm_c = sc ? 0.0f : x_c;
        const float4* gp = reinterpret_cast<const float4*>(gene_emb + (size_t)gd_c * H_DIM);
        const float4* tp = reinterpret_cast<const float4*>(tab + (size_t)row * H_DIM);
        #pragma unroll
        for (int q = 0; q < 4; ++q) {
            const int f = lane + 64 * q;
            g_c[q]  = gp[f];
            ta_c[q] = tp[2 * f];
            tb_c[q] = tp[2 * f + 1];
        }
    }

    #pragma unroll 8
    for (int i = 0; i < NITER; ++i) {
        const int t = w + i * S_LEN;

        // ---- issue scalars for i+2 (compile-time guard)
        float x_n2  = 0.0f;
        int   gd_n2 = 0;
        if (i + 2 < NITER) {
            x_n2  = expr[t + 2 * S_LEN];
            gd_n2 = gene_ids[t + 2 * S_LEN];
        }

        // ---- ballot + issue gene/tab staging for i+1
        float xm_n = 0.0f;
        float4 g_n[4], ta_n[4], tb_n[4];
        if (i + 1 < NITER) {
            const int rc = __popcll(__ballot(tka <= x_n)) + __popcll(__ballot(tkb <= x_n));
            const bool sn = (x_n < 0.0f);
            const int  mn = min(max(-((int)x_n) - 1, 0), NSPEC - 1);
            const int  rown = sn ? (HID_DIM + 1 + mn) : rc;
            xm_n = sn ? 0.0f : x_n;
            const float4* gp = reinterpret_cast<const float4*>(gene_emb + (size_t)gd_n * H_DIM);
            const float4* tp = reinterpret_cast<const float4*>(tab + (size_t)rown * H_DIM);
            #pragma unroll
            for (int q = 0; q < 4; ++q) {
                const int f = lane + 64 * q;
                g_n[q]  = gp[f];
                ta_n[q] = tp[2 * f];
                tb_n[q] = tp[2 * f + 1];
            }
        }

        // ---- consume current staging (one full body old): e + moments
        float4 e[4];
        float s1 = 0.0f, s2 = 0.0f;
        #pragma unroll
        for (int q = 0; q < 4; ++q) {
            float4 ev;
            ev.x = g_c[q].x + fmaf(xm_c, ta_c[q].x, ta_c[q].y) + p[q].x;
            ev.y = g_c[q].y + fmaf(xm_c, ta_c[q].z, ta_c[q].w) + p[q].y;
            ev.z = g_c[q].z + fmaf(xm_c, tb_c[q].x, tb_c[q].y) + p[q].z;
            ev.w = g_c[q].w + fmaf(xm_c, tb_c[q].z, tb_c[q].w) + p[q].w;
            e[q] = ev;
            s1 += ev.x + ev.y + ev.z + ev.w;
            s2 += ev.x * ev.x + ev.y * ev.y + ev.z * ev.z + ev.w * ev.w;
        }

        // ---- 64-lane butterfly reduction (no LDS, no barrier)
        #pragma unroll
        for (int off = 32; off >= 1; off >>= 1) {
            s1 += __shfl_xor(s1, off, 64);
            s2 += __shfl_xor(s2, off, 64);
        }

        const float inv  = 1.0f / (float)H_DIM;
        const float mu   = s1 * inv;
        const float rsig = rsqrtf(s2 * inv - mu * mu + LN_EPS);

        // ---- LN epilogue: gamma/beta from LDS, NT stores
        vfloat4* op = reinterpret_cast<vfloat4*>(out + (size_t)t * H_DIM);
        #pragma unroll
        for (int q = 0; q < 4; ++q) {
            const int f = lane + 64 * q;
            const float4 gm = gm_lds[f];
            const float4 bt = bt_lds[f];
            vfloat4 o;
            o.x = fmaf((e[q].x - mu) * rsig, gm.x, bt.x);
            o.y = fmaf((e[q].y - mu) * rsig, gm.y, bt.y);
            o.z = fmaf((e[q].z - mu) * rsig, gm.z, bt.z);
            o.w = fmaf((e[q].w - mu) * rsig, gm.w, bt.w);
            __builtin_nontemporal_store(o, op + f);
        }

        // ---- shift pipeline (all compile-time indexed; stays in registers)
        xm_c = xm_n;
        x_n  = x_n2;
        gd_n = gd_n2;
        #pragma unroll
        for (int q = 0; q < 4; ++q) {
            g_c[q]  = g_n[q];
            ta_c[q] = ta_n[q];
            tb_c[q] = tb_n[q];
        }
    }
}

// ---------------------------------------------------------------------------
extern "C" void kernel_launch(void* const* d_in, const int* in_sizes, int n_in,
                              void* d_out, int out_size, void* d_ws, size_t ws_size,
                              hipStream_t stream) {
    const int*   gene_ids = (const int*)  d_in[0];
    const float* expr     = (const float*)d_in[1];
    const float* gene_emb = (const float*)d_in[2];
    const float* W1       = (const float*)d_in[3];
    const float* b1       = (const float*)d_in[4];
    const float* W2       = (const float*)d_in[5];
    const float* b2       = (const float*)d_in[6];
    const float* spec     = (const float*)d_in[7];
    const float* pos_emb  = (const float*)d_in[8];
    const float* gamma    = (const float*)d_in[9];
    const float* beta     = (const float*)d_in[10];
    float* out = (float*)d_out;

    // workspace layout
    const size_t tab_bytes = (size_t)NROWS * H_DIM * sizeof(float2);  // ~1.07 MB
    float2* tab   = (float2*)d_ws;
    float*  tvals = (float*)((char*)d_ws + tab_bytes);

    const int n_tokens = in_sizes[0];   // B*S = 32768
    const int nwaves   = n_tokens / NITER;  // 4096 waves, one pos row each

    build_kernel<<<NROWS, 256, 0, stream>>>(W1, b1, W2, b2, spec, tvals, tab);
    fuse_kernel<<<nwaves / 4, 256, 0, stream>>>(gene_ids, expr, gene_emb, pos_emb,
                                                gamma, beta, tvals, tab, out);
}